// Round 9
// baseline (58.128 us; speedup 1.0000x reference)
//
#include <hip/hip_runtime.h>

#define MXN 2048   // MX == NY == 2048
#define DD  256
#define KK  100
#define KP  128    // K padded to MFMA granularity
#define NB  8

typedef __attribute__((ext_vector_type(8))) __bf16 bf16x8;
typedef __attribute__((ext_vector_type(4))) float  f32x4;

__device__ __forceinline__ unsigned short f2b(float f) {
  union { float f; unsigned u; } v; v.f = f;
  return (unsigned short)((v.u + 0x7fffu + ((v.u >> 16) & 1u)) >> 16);
}

// ---------------------------------------------------------------------------
// Kernel 0: At[k][d] = bf16(A[d][k]), zero-padded for k in [100,128). 64 KB.
// ---------------------------------------------------------------------------
__global__ __launch_bounds__(256) void k_At(const float* __restrict__ A,
                                            unsigned short* __restrict__ At) {
  int idx = blockIdx.x * 256 + threadIdx.x;   // 0 .. 128*256-1
  int k = idx >> 8, d = idx & 255;
  At[idx] = (k < KK) ? f2b(A[d * KK + k]) : (unsigned short)0;
}

// ---------------------------------------------------------------------------
// Kernel 1: XA = bf16(X @ A), sqX[r] = sum_k XA[r][k]^2.  (R4-proven body)
// LAUNCHED TWICE this round (idempotent) — double-launch ablation to measure
// k_proj's share of total time, since rocprof top-5 is saturated by fills.
// ---------------------------------------------------------------------------
__global__ __launch_bounds__(256) void k_proj(
    const float* __restrict__ X, const float* __restrict__ Y,
    const unsigned short* __restrict__ At,
    unsigned short* __restrict__ XAo, unsigned short* __restrict__ YAo,
    float* __restrict__ sqX, float* __restrict__ sqY)
{
  __shared__ __align__(16) unsigned short Ash[128 * 256]; // [k][d] swizzled, 64 KB

  const int bid = blockIdx.x;
  const bool isY = bid >= 256;
  const int row0 = (bid & 255) * 64;
  const float* __restrict__ src = isY ? Y : X;
  unsigned short* __restrict__ dst = isY ? YAo : XAo;
  float* __restrict__ sqdst = isY ? sqY : sqX;
  const int t = threadIdx.x;

#pragma unroll
  for (int i = 0; i < 16; ++i) {
    int ch = i * 256 + t;
    int row = ch >> 5, c = ch & 31;
    bf16x8 v = *reinterpret_cast<const bf16x8*>(At + ch * 8);
    int byte = (row * 512 + c * 16) ^ ((row & 7) << 4);
    *reinterpret_cast<bf16x8*>((char*)Ash + byte) = v;
  }
  __syncthreads();

  const int w = t >> 6, l = t & 63;
  const int lr = l & 15, lk8 = (l >> 4) * 8;
  const int rowA = row0 + w * 16 + lr;

  f32x4 acc[8];
#pragma unroll
  for (int j = 0; j < 8; ++j) acc[j] = (f32x4){0.f, 0.f, 0.f, 0.f};

#pragma unroll
  for (int ks = 0; ks < 8; ++ks) {
    const int d = ks * 32 + lk8;
    const float* px = src + (size_t)rowA * DD + d;
    float4 v0 = *reinterpret_cast<const float4*>(px);
    float4 v1 = *reinterpret_cast<const float4*>(px + 4);
    bf16x8 af;
    af[0] = (__bf16)v0.x; af[1] = (__bf16)v0.y; af[2] = (__bf16)v0.z; af[3] = (__bf16)v0.w;
    af[4] = (__bf16)v1.x; af[5] = (__bf16)v1.y; af[6] = (__bf16)v1.z; af[7] = (__bf16)v1.w;
#pragma unroll
    for (int nf = 0; nf < 8; ++nf) {
      const int kq = nf * 16 + lr;
      bf16x8 bf = *reinterpret_cast<bf16x8*>(
          (char*)Ash + ((kq * 512 + d * 2) ^ ((kq & 7) << 4)));
      acc[nf] = __builtin_amdgcn_mfma_f32_16x16x32_bf16(af, bf, acc[nf], 0, 0, 0);
    }
  }

  float sq[4] = {0.f, 0.f, 0.f, 0.f};
#pragma unroll
  for (int nf = 0; nf < 8; ++nf)
#pragma unroll
    for (int reg = 0; reg < 4; ++reg) {
      union { __bf16 b; unsigned short u; } cv;
      cv.b = (__bf16)acc[nf][reg];
      float vq = (float)cv.b;
      int r = row0 + w * 16 + ((l >> 4) << 2) + reg;
      dst[(size_t)r * KP + nf * 16 + lr] = cv.u;
      sq[reg] += vq * vq;
    }
#pragma unroll
  for (int reg = 0; reg < 4; ++reg) {
    float s = sq[reg];
    s += __shfl_xor(s, 1);
    s += __shfl_xor(s, 2);
    s += __shfl_xor(s, 4);
    s += __shfl_xor(s, 8);
    if (lr == 0)
      sqdst[row0 + w * 16 + ((l >> 4) << 2) + reg] = s;
  }
}

// ---------------------------------------------------------------------------
// Kernel 2: (R8 body, unchanged) strip-persistent, Y-in-reg, Xsh dbuf,
// no-vmcnt-drain barrier.
// ---------------------------------------------------------------------------
__global__ __launch_bounds__(256) void k_cross(
    const unsigned short* __restrict__ XA, const unsigned short* __restrict__ YA,
    const float* __restrict__ sqX, const float* __restrict__ sqY,
    float* __restrict__ out)
{
  __shared__ __align__(16) unsigned short Xsh[2][128 * 128];  // 2x32 KB swizzled

  const int bid = blockIdx.x;
  const int b  = bid & 7;           // batch -> XCD pin
  const int n0 = (bid >> 3) * 32;   // 64 strips per batch
  const int t = threadIdx.x;
  const int w = t >> 6, l = t & 63;
  const int m_w = w * 32;           // wave's m-offset within the 128-tile
  const int lr = l & 15, lk = (l >> 4) * 8;

  bf16x8 yf[2][4];
#pragma unroll
  for (int i = 0; i < 2; ++i)
#pragma unroll
    for (int ks = 0; ks < 4; ++ks)
      yf[i][ks] = *reinterpret_cast<const bf16x8*>(
          YA + ((size_t)(b * MXN + n0 + i * 16 + lr) * KP + ks * 32 + lk));

  bf16x8 xr[8];
#pragma unroll
  for (int i = 0; i < 8; ++i) {
    int ch = i * 256 + t;
    int row = ch >> 4, c = ch & 15;
    xr[i] = *reinterpret_cast<const bf16x8*>(
        XA + ((size_t)(b * MXN + row) * KP + c * 8));
  }
#pragma unroll
  for (int i = 0; i < 8; ++i) {
    int ch = i * 256 + t;
    int row = ch >> 4, c = ch & 15;
    int byte = (row * 256 + c * 16) ^ ((row & 7) << 4);
    *reinterpret_cast<bf16x8*>((char*)Xsh[0] + byte) = xr[i];
  }

  float syv[2][4];
#pragma unroll
  for (int i = 0; i < 2; ++i)
#pragma unroll
    for (int reg = 0; reg < 4; ++reg)
      syv[i][reg] = sqY[b * MXN + n0 + i * 16 + ((l >> 4) << 2) + reg];

  int cur = 0;
  for (int mt = 0; mt < 16; ++mt) {
    asm volatile("s_waitcnt lgkmcnt(0)" ::: "memory");
    __builtin_amdgcn_s_barrier();
    asm volatile("" ::: "memory");

    if (mt < 15) {
#pragma unroll
      for (int i = 0; i < 8; ++i) {
        int ch = i * 256 + t;
        int row = ch >> 4, c = ch & 15;
        xr[i] = *reinterpret_cast<const bf16x8*>(
            XA + ((size_t)(b * MXN + (mt + 1) * 128 + row) * KP + c * 8));
      }
    }

    f32x4 acc[2][2];
#pragma unroll
    for (int i = 0; i < 2; ++i)
#pragma unroll
      for (int j = 0; j < 2; ++j) acc[i][j] = (f32x4){0.f, 0.f, 0.f, 0.f};

#pragma unroll
    for (int ks = 0; ks < 4; ++ks) {
      const int d2 = ks * 64 + lk * 2;   // byte offset within row
      int rm0 = m_w + lr, rm1 = m_w + 16 + lr;
      bf16x8 b0 = *reinterpret_cast<bf16x8*>(
          (char*)Xsh[cur] + ((rm0 * 256 + d2) ^ ((rm0 & 7) << 4)));
      bf16x8 b1 = *reinterpret_cast<bf16x8*>(
          (char*)Xsh[cur] + ((rm1 * 256 + d2) ^ ((rm1 & 7) << 4)));
      acc[0][0] = __builtin_amdgcn_mfma_f32_16x16x32_bf16(yf[0][ks], b0, acc[0][0], 0, 0, 0);
      acc[0][1] = __builtin_amdgcn_mfma_f32_16x16x32_bf16(yf[0][ks], b1, acc[0][1], 0, 0, 0);
      acc[1][0] = __builtin_amdgcn_mfma_f32_16x16x32_bf16(yf[1][ks], b0, acc[1][0], 0, 0, 0);
      acc[1][1] = __builtin_amdgcn_mfma_f32_16x16x32_bf16(yf[1][ks], b1, acc[1][1], 0, 0, 0);
    }

    float sx0 = sqX[b * MXN + mt * 128 + m_w + lr];
    float sx1 = sqX[b * MXN + mt * 128 + m_w + 16 + lr];
#pragma unroll
    for (int i = 0; i < 2; ++i)
#pragma unroll
      for (int reg = 0; reg < 4; ++reg) {
        int n = n0 + i * 16 + ((l >> 4) << 2) + reg;
        size_t obase = ((size_t)b * MXN + n) * MXN + mt * 128 + m_w;
        float v0 = syv[i][reg] + sx0 - 2.0f * acc[i][0][reg];
        float v1 = syv[i][reg] + sx1 - 2.0f * acc[i][1][reg];
        out[obase + lr]      = v0 > 0.f ? v0 : 0.f;
        out[obase + 16 + lr] = v1 > 0.f ? v1 : 0.f;
      }

    if (mt < 15) {
#pragma unroll
      for (int i = 0; i < 8; ++i) {
        int ch = i * 256 + t;
        int row = ch >> 4, c = ch & 15;
        int byte = (row * 256 + c * 16) ^ ((row & 7) << 4);
        *reinterpret_cast<bf16x8*>((char*)Xsh[cur ^ 1] + byte) = xr[i];
      }
    }
    cur ^= 1;
  }
}

extern "C" void kernel_launch(void* const* d_in, const int* in_sizes, int n_in,
                              void* d_out, int out_size, void* d_ws, size_t ws_size,
                              hipStream_t stream) {
  const float* X = (const float*)d_in[0];   // (8, 2048, 256)
  const float* Y = (const float*)d_in[1];   // (8, 2048, 256)
  const float* A = (const float*)d_in[2];   // (256, 100)
  float* out = (float*)d_out;               // (8, 2048, 2048)

  char* ws = (char*)d_ws;
  const size_t ROWS = (size_t)NB * MXN;     // 16384
  unsigned short* XAw = (unsigned short*)ws;                        // 4 MB
  unsigned short* YAw = (unsigned short*)(ws + ROWS * KP * 2);      // 4 MB
  float* sqX = (float*)(ws + 2 * ROWS * KP * 2);                    // 64 KB
  float* sqY = (float*)(ws + 2 * ROWS * KP * 2 + ROWS * 4);         // 64 KB
  unsigned short* At = (unsigned short*)(ws + 2 * ROWS * KP * 2 + 2 * ROWS * 4); // 64 KB

  k_At  <<<128, 256, 0, stream>>>(A, At);
  k_proj<<<512, 256, 0, stream>>>(X, Y, At, XAw, YAw, sqX, sqY);
  k_proj<<<512, 256, 0, stream>>>(X, Y, At, XAw, YAw, sqX, sqY);  // ABLATION: 2nd identical launch
  k_cross<<<512, 256, 0, stream>>>(XAw, YAw, sqX, sqY, out);
}

// Round 10
// 46.863 us; speedup vs baseline: 1.2404x; 1.2404x over previous
//
#include <hip/hip_runtime.h>

#define MXN 2048   // MX == NY == 2048
#define DD  256
#define KK  100
#define KP  128    // K padded to MFMA granularity
#define NB  8

typedef __attribute__((ext_vector_type(8))) __bf16 bf16x8;
typedef __attribute__((ext_vector_type(4))) float  f32x4;

__device__ __forceinline__ unsigned short f2b(float f) {
  union { float f; unsigned u; } v; v.f = f;
  return (unsigned short)((v.u + 0x7fffu + ((v.u >> 16) & 1u)) >> 16);
}

// ---------------------------------------------------------------------------
// Kernel 0: At[k][d] = bf16(A[d][k]), zero-padded for k in [100,128). 64 KB.
// ---------------------------------------------------------------------------
__global__ __launch_bounds__(256) void k_At(const float* __restrict__ A,
                                            unsigned short* __restrict__ At) {
  int idx = blockIdx.x * 256 + threadIdx.x;   // 0 .. 128*256-1
  int k = idx >> 8, d = idx & 255;
  At[idx] = (k < KK) ? f2b(A[d * KK + k]) : (unsigned short)0;
}

// ---------------------------------------------------------------------------
// Kernel 1: XA = bf16(X @ A), sqX[r] = sum_k XA[r][k]^2.  (R4-proven body)
// Measured R9: ~9.5 us (near its ~7 us floor).
// ---------------------------------------------------------------------------
__global__ __launch_bounds__(256) void k_proj(
    const float* __restrict__ X, const float* __restrict__ Y,
    const unsigned short* __restrict__ At,
    unsigned short* __restrict__ XAo, unsigned short* __restrict__ YAo,
    float* __restrict__ sqX, float* __restrict__ sqY)
{
  __shared__ __align__(16) unsigned short Ash[128 * 256]; // [k][d] swizzled, 64 KB

  const int bid = blockIdx.x;
  const bool isY = bid >= 256;
  const int row0 = (bid & 255) * 64;
  const float* __restrict__ src = isY ? Y : X;
  unsigned short* __restrict__ dst = isY ? YAo : XAo;
  float* __restrict__ sqdst = isY ? sqY : sqX;
  const int t = threadIdx.x;

#pragma unroll
  for (int i = 0; i < 16; ++i) {
    int ch = i * 256 + t;
    int row = ch >> 5, c = ch & 31;
    bf16x8 v = *reinterpret_cast<const bf16x8*>(At + ch * 8);
    int byte = (row * 512 + c * 16) ^ ((row & 7) << 4);
    *reinterpret_cast<bf16x8*>((char*)Ash + byte) = v;
  }
  __syncthreads();

  const int w = t >> 6, l = t & 63;
  const int lr = l & 15, lk8 = (l >> 4) * 8;
  const int rowA = row0 + w * 16 + lr;

  f32x4 acc[8];
#pragma unroll
  for (int j = 0; j < 8; ++j) acc[j] = (f32x4){0.f, 0.f, 0.f, 0.f};

#pragma unroll
  for (int ks = 0; ks < 8; ++ks) {
    const int d = ks * 32 + lk8;
    const float* px = src + (size_t)rowA * DD + d;
    float4 v0 = *reinterpret_cast<const float4*>(px);
    float4 v1 = *reinterpret_cast<const float4*>(px + 4);
    bf16x8 af;
    af[0] = (__bf16)v0.x; af[1] = (__bf16)v0.y; af[2] = (__bf16)v0.z; af[3] = (__bf16)v0.w;
    af[4] = (__bf16)v1.x; af[5] = (__bf16)v1.y; af[6] = (__bf16)v1.z; af[7] = (__bf16)v1.w;
#pragma unroll
    for (int nf = 0; nf < 8; ++nf) {
      const int kq = nf * 16 + lr;
      bf16x8 bf = *reinterpret_cast<bf16x8*>(
          (char*)Ash + ((kq * 512 + d * 2) ^ ((kq & 7) << 4)));
      acc[nf] = __builtin_amdgcn_mfma_f32_16x16x32_bf16(af, bf, acc[nf], 0, 0, 0);
    }
  }

  float sq[4] = {0.f, 0.f, 0.f, 0.f};
#pragma unroll
  for (int nf = 0; nf < 8; ++nf)
#pragma unroll
    for (int reg = 0; reg < 4; ++reg) {
      union { __bf16 b; unsigned short u; } cv;
      cv.b = (__bf16)acc[nf][reg];
      float vq = (float)cv.b;
      int r = row0 + w * 16 + ((l >> 4) << 2) + reg;
      dst[(size_t)r * KP + nf * 16 + lr] = cv.u;
      sq[reg] += vq * vq;
    }
#pragma unroll
  for (int reg = 0; reg < 4; ++reg) {
    float s = sq[reg];
    s += __shfl_xor(s, 1);
    s += __shfl_xor(s, 2);
    s += __shfl_xor(s, 4);
    s += __shfl_xor(s, 8);
    if (lr == 0)
      sqdst[row0 + w * 16 + ((l >> 4) << 2) + reg] = s;
  }
}

// ---------------------------------------------------------------------------
// Kernel 2 (v8): 1024 blocks = (batch b = bid&7) x (32-row n-strip) x
// (m-half of 8 tiles). 4 blocks/CU (32 KB single-buffer Xsh, VGPR<=128) so
// independent blocks decorrelate load/LDS/store phases that the per-tile
// barrier serializes within a block. T14: tile t+1's global loads issue
// right after barrier B of tile t; their (in-order, counted) vmcnt wait is
// next iteration's ds_write — one full compute phase of latency hiding; no
// store drain anywhere (lgkm-only barriers).
// ---------------------------------------------------------------------------
__global__ __launch_bounds__(256, 4) void k_cross(
    const unsigned short* __restrict__ XA, const unsigned short* __restrict__ YA,
    const float* __restrict__ sqX, const float* __restrict__ sqY,
    float* __restrict__ out)
{
  __shared__ __align__(16) unsigned short Xsh[128 * 128];  // 32 KB swizzled

  const int bid = blockIdx.x;
  const int b   = bid & 7;             // batch -> XCD pin
  const int sh_ = bid >> 3;            // 0..127
  const int n0  = (sh_ >> 1) * 32;     // 64 strips per batch
  const int mh  = (sh_ & 1) * 8;       // m-tile half: tiles [mh, mh+8)
  const int t = threadIdx.x;
  const int w = t >> 6, l = t & 63;
  const int m_w = w * 32;              // wave's m-offset within a 128-tile
  const int lr = l & 15, lk = (l >> 4) * 8;

  // Y fragments, once: rows n0+i*16+lr, cols ks*32+lk..+8.  (32 VGPR)
  bf16x8 yf[2][4];
#pragma unroll
  for (int i = 0; i < 2; ++i)
#pragma unroll
    for (int ks = 0; ks < 4; ++ks)
      yf[i][ks] = *reinterpret_cast<const bf16x8*>(
          YA + ((size_t)(b * MXN + n0 + i * 16 + lr) * KP + ks * 32 + lk));

  // This lane's 8 sqY values.
  float syv[2][4];
#pragma unroll
  for (int i = 0; i < 2; ++i)
#pragma unroll
    for (int reg = 0; reg < 4; ++reg)
      syv[i][reg] = sqY[b * MXN + n0 + i * 16 + ((l >> 4) << 2) + reg];

  // Prefetch first tile into regs.
  bf16x8 xr[8];
#pragma unroll
  for (int i = 0; i < 8; ++i) {
    int ch = i * 256 + t;
    int row = ch >> 4, c = ch & 15;
    xr[i] = *reinterpret_cast<const bf16x8*>(
        XA + ((size_t)(b * MXN + mh * 128 + row) * KP + c * 8));
  }

  for (int it = 0; it < 8; ++it) {
    const int mt = mh + it;

    // Barrier A: all waves finished reading Xsh for the previous tile.
    asm volatile("s_waitcnt lgkmcnt(0)" ::: "memory");
    __builtin_amdgcn_s_barrier();
    asm volatile("" ::: "memory");

    // Write tile mt into Xsh (vmcnt wait for xr loads is counted, in-order:
    // stores issued after them keep flowing).
#pragma unroll
    for (int i = 0; i < 8; ++i) {
      int ch = i * 256 + t;
      int row = ch >> 4, c = ch & 15;
      int byte = (row * 256 + c * 16) ^ ((row & 7) << 4);
      *reinterpret_cast<bf16x8*>((char*)Xsh + byte) = xr[i];
    }

    // Barrier B: Xsh visible to all waves.
    asm volatile("s_waitcnt lgkmcnt(0)" ::: "memory");
    __builtin_amdgcn_s_barrier();
    asm volatile("" ::: "memory");

    // Issue next tile's loads now; consumed by NEXT iteration's ds_write.
    if (it < 7) {
#pragma unroll
      for (int i = 0; i < 8; ++i) {
        int ch = i * 256 + t;
        int row = ch >> 4, c = ch & 15;
        xr[i] = *reinterpret_cast<const bf16x8*>(
            XA + ((size_t)(b * MXN + (mt + 1) * 128 + row) * KP + c * 8));
      }
    }

    // Compute 32n x 32m per wave: 2x2 frags, K = 128 in 4 steps.
    f32x4 acc[2][2];
#pragma unroll
    for (int i = 0; i < 2; ++i)
#pragma unroll
      for (int j = 0; j < 2; ++j) acc[i][j] = (f32x4){0.f, 0.f, 0.f, 0.f};

#pragma unroll
    for (int ks = 0; ks < 4; ++ks) {
      const int d2 = ks * 64 + lk * 2;   // byte offset within row
      int rm0 = m_w + lr, rm1 = m_w + 16 + lr;
      bf16x8 b0 = *reinterpret_cast<bf16x8*>(
          (char*)Xsh + ((rm0 * 256 + d2) ^ ((rm0 & 7) << 4)));
      bf16x8 b1 = *reinterpret_cast<bf16x8*>(
          (char*)Xsh + ((rm1 * 256 + d2) ^ ((rm1 & 7) << 4)));
      acc[0][0] = __builtin_amdgcn_mfma_f32_16x16x32_bf16(yf[0][ks], b0, acc[0][0], 0, 0, 0);
      acc[0][1] = __builtin_amdgcn_mfma_f32_16x16x32_bf16(yf[0][ks], b1, acc[0][1], 0, 0, 0);
      acc[1][0] = __builtin_amdgcn_mfma_f32_16x16x32_bf16(yf[1][ks], b0, acc[1][0], 0, 0, 0);
      acc[1][1] = __builtin_amdgcn_mfma_f32_16x16x32_bf16(yf[1][ks], b1, acc[1][1], 0, 0, 0);
    }

    // Epilogue.
    float sx0 = sqX[b * MXN + mt * 128 + m_w + lr];
    float sx1 = sqX[b * MXN + mt * 128 + m_w + 16 + lr];
#pragma unroll
    for (int i = 0; i < 2; ++i)
#pragma unroll
      for (int reg = 0; reg < 4; ++reg) {
        int n = n0 + i * 16 + ((l >> 4) << 2) + reg;
        size_t obase = ((size_t)b * MXN + n) * MXN + mt * 128 + m_w;
        float v0 = syv[i][reg] + sx0 - 2.0f * acc[i][0][reg];
        float v1 = syv[i][reg] + sx1 - 2.0f * acc[i][1][reg];
        out[obase + lr]      = v0 > 0.f ? v0 : 0.f;
        out[obase + 16 + lr] = v1 > 0.f ? v1 : 0.f;
      }
  }
}

extern "C" void kernel_launch(void* const* d_in, const int* in_sizes, int n_in,
                              void* d_out, int out_size, void* d_ws, size_t ws_size,
                              hipStream_t stream) {
  const float* X = (const float*)d_in[0];   // (8, 2048, 256)
  const float* Y = (const float*)d_in[1];   // (8, 2048, 256)
  const float* A = (const float*)d_in[2];   // (256, 100)
  float* out = (float*)d_out;               // (8, 2048, 2048)

  char* ws = (char*)d_ws;
  const size_t ROWS = (size_t)NB * MXN;     // 16384
  unsigned short* XAw = (unsigned short*)ws;                        // 4 MB
  unsigned short* YAw = (unsigned short*)(ws + ROWS * KP * 2);      // 4 MB
  float* sqX = (float*)(ws + 2 * ROWS * KP * 2);                    // 64 KB
  float* sqY = (float*)(ws + 2 * ROWS * KP * 2 + ROWS * 4);         // 64 KB
  unsigned short* At = (unsigned short*)(ws + 2 * ROWS * KP * 2 + 2 * ROWS * 4); // 64 KB

  k_At  <<<128, 256, 0, stream>>>(A, At);
  k_proj<<<512, 256, 0, stream>>>(X, Y, At, XAw, YAw, sqX, sqY);
  k_cross<<<1024, 256, 0, stream>>>(XAw, YAw, sqX, sqY, out);
}